// Round 11
// baseline (1071.316 us; speedup 1.0000x reference)
//
#include <hip/hip_runtime.h>

#define NN 16384
#define NF 512
#define NH 64
#define NC 40
#define KSTEPS 10
#define KSPLIT 8          // waves per block in stepf (fallback)
#define BM 32             // rows per block in stepf
#define PKH 8             // K-split factor across blocks (stept/step0)
#define ASCALE 8192.0f    // adj fp8 pre-scale (power of 2, exact)

typedef __attribute__((ext_vector_type(8))) short short8;
typedef __attribute__((ext_vector_type(4))) float f32x4;
typedef __attribute__((ext_vector_type(2))) long longx2;

__device__ __forceinline__ unsigned short f2bf(float f) {
    unsigned int u = __float_as_uint(f);
    u += 0x7FFFu + ((u >> 16) & 1u);   // RNE
    return (unsigned short)(u >> 16);
}
__device__ __forceinline__ float bf2f(unsigned short h) {
    return __uint_as_float((unsigned int)h << 16);
}
__device__ __forceinline__ short8 cvt8(float4 f0, float4 f1) {
    short8 r;
    r[0] = (short)f2bf(f0.x); r[1] = (short)f2bf(f0.y);
    r[2] = (short)f2bf(f0.z); r[3] = (short)f2bf(f0.w);
    r[4] = (short)f2bf(f1.x); r[5] = (short)f2bf(f1.y);
    r[6] = (short)f2bf(f1.z); r[7] = (short)f2bf(f1.w);
    return r;
}
// 4 f32 -> 4 packed OCP e4m3 bytes (HW cvt, RNE)
__device__ __forceinline__ int pack4fp8(float x0, float x1, float x2, float x3) {
    int r = __builtin_amdgcn_cvt_pk_fp8_f32(x0, x1, 0, false);
    return __builtin_amdgcn_cvt_pk_fp8_f32(x2, x3, r, true);
}
__device__ __forceinline__ longx2 ntload_l2(const unsigned char* p) {
    return __builtin_nontemporal_load((const longx2*)p);
}

// ---------------------------------------------------------------------------
// h0T[c][r] = relu(x @ W1)[r][c]  (bf16, transposed layout)
// ---------------------------------------------------------------------------
__global__ __launch_bounds__(256) void h0_kernel(const float* __restrict__ x,
                                                 const float* __restrict__ W1,
                                                 unsigned short* __restrict__ h0T) {
    const int t  = threadIdx.x;
    const int rl = t & 63;
    const int w  = t >> 6;
    const size_t r = (size_t)blockIdx.x * 64 + rl;
    const float* xr = x + r * NF;

    float acc[16];
#pragma unroll
    for (int j = 0; j < 16; ++j) acc[j] = 0.f;

    for (int k = 0; k < NF; k += 4) {
        float4 xv = *(const float4*)&xr[k];
#pragma unroll
        for (int i = 0; i < 4; ++i) {
            float xs = (i == 0) ? xv.x : (i == 1) ? xv.y : (i == 2) ? xv.z : xv.w;
            const float* wr = W1 + (size_t)(k + i) * NH + w * 16;
#pragma unroll
            for (int j = 0; j < 16; ++j) acc[j] = fmaf(xs, wr[j], acc[j]);
        }
    }
#pragma unroll
    for (int j = 0; j < 16; ++j)
        h0T[(size_t)(w * 16 + j) * NN + r] = f2bf(fmaxf(acc[j], 0.f));
}

// ---------------------------------------------------------------------------
// Step 0 (rewritten): block = (mt 16-row stripe) x (kh 2048-K slab, kh=bid&7
// = XCD id so the bf16 B-slab stays L2-hot). Per 1024-col chunk:
//  - stage: each wave reads its 2 rows SEQUENTIALLY (1 KiB wave-loads,
//    4 KiB/row/chunk), converts f32->bf16, ds_write to padded LDS tile.
//  - consume: per 64-col tile, ds_read A-frags (uniform bank spread),
//    reuse the SAME regs for fp8 x ASCALE conversion -> contiguous 1 KiB
//    wave-store to tiled adjT8; bf16 MFMA vs global B (=h0T, L2-hot).
//  - 8-wave LDS reduce -> bf16 partials P[kh]. combine_kernel finishes.
// adjT8 layout (unchanged): byte ((mt*256+ktg)*1024 + (fg*16+fr)*16 + h*8+j)
//   = ASCALE * adj[mt*16+fr][ktg*64 + 32h + 8fg + j]
// ---------------------------------------------------------------------------
__global__ __launch_bounds__(512, 4) void step0_kernel(
        const float* __restrict__ adj,
        unsigned char* __restrict__ adjT8,
        const unsigned short* __restrict__ xT,
        unsigned short* __restrict__ P) {
    __shared__ __align__(16) unsigned char SMEM[33280];
    unsigned short (*AT)[1032] = (unsigned short (*)[1032])SMEM;  // 16 x 1032 bf16
    float (*FB)[16][65] = (float (*)[16][65])SMEM;                // 8 x 16 x 65 f32

    const int t  = threadIdx.x;
    const int l  = t & 63;
    const int w  = t >> 6;
    const int fr = l & 15;
    const int fg = l >> 4;
    const int kh = blockIdx.x & 7;
    const int mt = blockIdx.x >> 3;          // 0..1023
    const int r0 = mt * 16;
    const long ks0 = (long)kh * (NN / PKH);  // 2048-wide K slab

    f32x4 acc[4];
#pragma unroll
    for (int ni = 0; ni < 4; ++ni) acc[ni] = (f32x4){0.f, 0.f, 0.f, 0.f};

#pragma unroll
    for (int chunk = 0; chunk < 2; ++chunk) {
        const long kc0 = ks0 + chunk * 1024;
        __syncthreads();   // protect AT from previous chunk's readers
        // ---- stage: wave w handles rows 2w, 2w+1, sequential reads ----
#pragma unroll
        for (int rr = 0; rr < 2; ++rr) {
            const int row = 2 * w + rr;
            const float* src = &adj[(size_t)(r0 + row) * NN + kc0];
#pragma unroll
            for (int q = 0; q < 4; ++q) {
                float4 v = *(const float4*)&src[q * 256 + l * 4];
                ushort4 o;
                o.x = f2bf(v.x); o.y = f2bf(v.y); o.z = f2bf(v.z); o.w = f2bf(v.w);
                *(ushort4*)&AT[row][q * 256 + l * 4] = o;
            }
        }
        __syncthreads();
        // ---- consume: wave w handles tiles 2w, 2w+1 of this chunk ----
#pragma unroll
        for (int tt = 0; tt < 2; ++tt) {
            const int tl = 2 * w + tt;
            short8 a0 = *(const short8*)&AT[fr][tl * 64 + 8 * fg];
            short8 a1 = *(const short8*)&AT[fr][tl * 64 + 32 + 8 * fg];

            // fp8 writeout: lane l emits bytes l*16..+15 of tile (mt, ktg)
            int4 pk;
            pk.x = pack4fp8(ASCALE * bf2f((unsigned short)a0[0]),
                            ASCALE * bf2f((unsigned short)a0[1]),
                            ASCALE * bf2f((unsigned short)a0[2]),
                            ASCALE * bf2f((unsigned short)a0[3]));
            pk.y = pack4fp8(ASCALE * bf2f((unsigned short)a0[4]),
                            ASCALE * bf2f((unsigned short)a0[5]),
                            ASCALE * bf2f((unsigned short)a0[6]),
                            ASCALE * bf2f((unsigned short)a0[7]));
            pk.z = pack4fp8(ASCALE * bf2f((unsigned short)a1[0]),
                            ASCALE * bf2f((unsigned short)a1[1]),
                            ASCALE * bf2f((unsigned short)a1[2]),
                            ASCALE * bf2f((unsigned short)a1[3]));
            pk.w = pack4fp8(ASCALE * bf2f((unsigned short)a1[4]),
                            ASCALE * bf2f((unsigned short)a1[5]),
                            ASCALE * bf2f((unsigned short)a1[6]),
                            ASCALE * bf2f((unsigned short)a1[7]));
            const size_t st = ((size_t)mt * 256 + kh * 32 + chunk * 16 + tl) * 1024
                              + (size_t)l * 16;
            *(int4*)&adjT8[st] = pk;

            // bf16 MFMA vs global B (L2-hot slab)
            const long kb = kc0 + tl * 64 + 8 * fg;
#pragma unroll
            for (int ni = 0; ni < 4; ++ni) {
                short8 b0 = *(const short8*)&xT[(size_t)(16 * ni + fr) * NN + kb];
                short8 b1 = *(const short8*)&xT[(size_t)(16 * ni + fr) * NN + kb + 32];
                acc[ni] = __builtin_amdgcn_mfma_f32_16x16x32_bf16(a0, b0, acc[ni], 0, 0, 0);
                acc[ni] = __builtin_amdgcn_mfma_f32_16x16x32_bf16(a1, b1, acc[ni], 0, 0, 0);
            }
        }
    }

    // ---- 8-wave reduce -> bf16 partials ----
    __syncthreads();
#pragma unroll
    for (int ni = 0; ni < 4; ++ni)
#pragma unroll
        for (int r = 0; r < 4; ++r)
            FB[w][4 * fg + r][16 * ni + fr] = acc[ni][r];
    __syncthreads();

    const int col = t & 63;
    const int rw2 = t >> 6;
#pragma unroll
    for (int rr = 0; rr < 2; ++rr) {
        const int row = 2 * rw2 + rr;
        float s = 0.f;
#pragma unroll
        for (int ww = 0; ww < 8; ++ww) s += FB[ww][row][col];
        P[((size_t)kh * NN + r0 + row) * 64 + col] = f2bf(s);
    }
}

// ---------------------------------------------------------------------------
// Steps 1..9: fp8 x fp8 MFMA. BM=256 rows/block, 8 waves split M, K split 8x
// across blocks (kh = bid&7). B staged per k64-iter into LDS (fragment
// layout, double-buffered); A = tiled fp8 nt stream. Partials -> P (bf16).
// ---------------------------------------------------------------------------
__global__ __launch_bounds__(512, 4) void stept_kernel(
        const unsigned char* __restrict__ adjT8,
        const unsigned char* __restrict__ xT8,
        unsigned short* __restrict__ P) {
    __shared__ unsigned char BLF[2][4096];   // 8 KiB, fragment-layout fp8 B

    const int t  = threadIdx.x;
    const int l  = t & 63;
    const int w  = t >> 6;
    const int fr = l & 15;
    const int fg = l >> 4;
    const int kh = blockIdx.x & 7;
    const int rt = blockIdx.x >> 3;
    const int kb0 = kh * (NN / PKH);

    const unsigned char* At0 = adjT8
        + (((size_t)(rt * 16 + 2 * w) * 256) + (size_t)(kh * 32)) * 1024 + (size_t)l * 16;
    const unsigned char* At1 = At0 + (size_t)256 * 1024;

    const size_t bsrc = (size_t)(16 * (w >> 1) + fr) * NN + 32 * (w & 1) + 8 * fg;
    unsigned char* st0 = &BLF[0][t * 8];
    unsigned char* st1 = &BLF[1][t * 8];

    f32x4 acc[2][4];
#pragma unroll
    for (int mi = 0; mi < 2; ++mi)
#pragma unroll
        for (int ni = 0; ni < 4; ++ni) acc[mi][ni] = (f32x4){0.f, 0.f, 0.f, 0.f};

    *(long*)st0 = *(const long*)&xT8[bsrc + kb0];
    __syncthreads();

#pragma unroll 2
    for (int i = 0; i < 32; ++i) {
        const unsigned char* rdbuf = (i & 1) ? BLF[1] : BLF[0];
        unsigned char* stbuf = (i & 1) ? st0 : st1;
        if (i + 1 < 32)
            *(long*)stbuf = *(const long*)&xT8[bsrc + kb0 + (i + 1) * 64];

        longx2 a0 = ntload_l2(At0);
        longx2 a1 = ntload_l2(At1);
        At0 += 1024;
        At1 += 1024;

        long b[4][2];
#pragma unroll
        for (int ni = 0; ni < 4; ++ni)
#pragma unroll
            for (int h = 0; h < 2; ++h)
                b[ni][h] = *(const long*)&rdbuf[(size_t)((ni * 2 + h) * 64 + l) * 8];

#pragma unroll
        for (int ni = 0; ni < 4; ++ni) {
            acc[0][ni] = __builtin_amdgcn_mfma_f32_16x16x32_fp8_fp8(a0.x, b[ni][0], acc[0][ni], 0, 0, 0);
            acc[0][ni] = __builtin_amdgcn_mfma_f32_16x16x32_fp8_fp8(a0.y, b[ni][1], acc[0][ni], 0, 0, 0);
            acc[1][ni] = __builtin_amdgcn_mfma_f32_16x16x32_fp8_fp8(a1.x, b[ni][0], acc[1][ni], 0, 0, 0);
            acc[1][ni] = __builtin_amdgcn_mfma_f32_16x16x32_fp8_fp8(a1.y, b[ni][1], acc[1][ni], 0, 0, 0);
        }
        __syncthreads();
    }

    const size_t rowbase = (size_t)rt * 256 + w * 32;
#pragma unroll
    for (int mi = 0; mi < 2; ++mi)
#pragma unroll
        for (int ni = 0; ni < 4; ++ni)
#pragma unroll
            for (int r = 0; r < 4; ++r)
                P[(((size_t)kh * NN) + rowbase + mi * 16 + 4 * fg + r) * 64 + 16 * ni + fr]
                    = f2bf(acc[mi][ni][r]);
}

// ---------------------------------------------------------------------------
// Combine: val = scale * sum_kh P[kh] + 0.1 * h0T  (scale = 0.9 for step 0,
// 0.9/ASCALE for fp8 steps); writes bf16 xnT AND fp8 xnT8.
// ---------------------------------------------------------------------------
__global__ __launch_bounds__(256) void combine_kernel(
        const unsigned short* __restrict__ P,
        const unsigned short* __restrict__ h0T,
        unsigned short* __restrict__ xnT,
        unsigned char* __restrict__ xnT8,
        float scale) {
    __shared__ float LS[64][65];
    const int t  = threadIdx.x;
    const int r0 = blockIdx.x * 64;

    {   // phase 1: sum bf16 partials, row-major
        const int rl = t >> 2;
        const int c0 = (t & 3) * 16;
        float s[16];
#pragma unroll
        for (int j = 0; j < 16; ++j) s[j] = 0.f;
#pragma unroll
        for (int kh = 0; kh < PKH; ++kh) {
            const unsigned short* p = &P[(((size_t)kh * NN) + r0 + rl) * 64 + c0];
            short8 v0 = *(const short8*)&p[0];
            short8 v1 = *(const short8*)&p[8];
#pragma unroll
            for (int j = 0; j < 8; ++j) {
                s[j]     += bf2f((unsigned short)v0[j]);
                s[8 + j] += bf2f((unsigned short)v1[j]);
            }
        }
#pragma unroll
        for (int j = 0; j < 16; ++j) LS[rl][c0 + j] = s[j];
    }
    __syncthreads();

    {   // phase 2: transpose + epilogue + bf16/fp8 stores
        const int c  = t >> 2;
        const int rs = (t & 3) * 16;
        float vf[16];
        short8 v[2];
#pragma unroll
        for (int j = 0; j < 16; ++j) {
            vf[j] = scale * LS[rs + j][c]
                  + 0.1f * bf2f(h0T[(size_t)c * NN + r0 + rs + j]);
            v[j >> 3][j & 7] = (short)f2bf(vf[j]);
        }
        *(short8*)&xnT[(size_t)c * NN + r0 + rs]     = v[0];
        *(short8*)&xnT[(size_t)c * NN + r0 + rs + 8] = v[1];
        int4 pk;
        pk.x = pack4fp8(vf[0],  vf[1],  vf[2],  vf[3]);
        pk.y = pack4fp8(vf[4],  vf[5],  vf[6],  vf[7]);
        pk.z = pack4fp8(vf[8],  vf[9],  vf[10], vf[11]);
        pk.w = pack4fp8(vf[12], vf[13], vf[14], vf[15]);
        *(int4*)&xnT8[(size_t)c * NN + r0 + rs] = pk;
    }
}

// ---------------------------------------------------------------------------
// Fallback (tiny workspace): fp32 adj on the fly, bf16 MFMA, untiled.
// ---------------------------------------------------------------------------
__device__ __forceinline__ void finish_blockf(float buf[KSPLIT][BM][65],
                                              const f32x4 (&acc)[2][4],
                                              int t, int l, int w, int row0,
                                              const unsigned short* __restrict__ h0T,
                                              unsigned short* __restrict__ xnT) {
    const int fr = l & 15;
    const int fg = l >> 4;
#pragma unroll
    for (int mi = 0; mi < 2; ++mi)
#pragma unroll
        for (int ni = 0; ni < 4; ++ni)
#pragma unroll
            for (int r = 0; r < 4; ++r)
                buf[w][16 * mi + 4 * fg + r][16 * ni + fr] = acc[mi][ni][r];
    __syncthreads();

    const int col = t >> 3;
    const int rb  = 4 * (t & 7);
    float s0 = 0.f, s1 = 0.f, s2 = 0.f, s3 = 0.f;
#pragma unroll
    for (int ww = 0; ww < KSPLIT; ++ww) {
        s0 += buf[ww][rb + 0][col];
        s1 += buf[ww][rb + 1][col];
        s2 += buf[ww][rb + 2][col];
        s3 += buf[ww][rb + 3][col];
    }
    const size_t base = (size_t)col * NN + row0 + rb;
    ushort4 h4 = *(const ushort4*)&h0T[base];
    ushort4 o;
    o.x = f2bf(0.9f * s0 + 0.1f * bf2f(h4.x));
    o.y = f2bf(0.9f * s1 + 0.1f * bf2f(h4.y));
    o.z = f2bf(0.9f * s2 + 0.1f * bf2f(h4.z));
    o.w = f2bf(0.9f * s3 + 0.1f * bf2f(h4.w));
    *(ushort4*)&xnT[base] = o;
}

__global__ __launch_bounds__(512, 4) void stepf_kernel(
        const float* __restrict__ adj,
        const unsigned short* __restrict__ xT,
        const unsigned short* __restrict__ h0T,
        unsigned short* __restrict__ xnT) {
    __shared__ float buf[KSPLIT][BM][65];

    const int t    = threadIdx.x;
    const int l    = t & 63;
    const int w    = t >> 6;
    const int fr   = l & 15;
    const int row0 = blockIdx.x * BM;

    const size_t a0 = (size_t)(row0 + fr) * NN;
    const size_t a1 = a0 + (size_t)16 * NN;
    const long   kbase = (long)w * (NN / KSPLIT) + 8 * (l >> 4);

    f32x4 acc[2][4];
#pragma unroll
    for (int mi = 0; mi < 2; ++mi)
#pragma unroll
        for (int ni = 0; ni < 4; ++ni) acc[mi][ni] = (f32x4){0.f, 0.f, 0.f, 0.f};

    for (int kk = 0; kk < NN / KSPLIT; kk += 64) {
        const long kb = kbase + kk;
        short8 a[2][2], b[4][2];
#pragma unroll
        for (int mi = 0; mi < 2; ++mi) {
            const size_t ab = (mi ? a1 : a0);
#pragma unroll
            for (int h = 0; h < 2; ++h) {
                float4 f0 = *(const float4*)&adj[ab + kb + 32 * h];
                float4 f1 = *(const float4*)&adj[ab + kb + 32 * h + 4];
                a[mi][h] = cvt8(f0, f1);
            }
        }
#pragma unroll
        for (int ni = 0; ni < 4; ++ni)
#pragma unroll
            for (int h = 0; h < 2; ++h)
                b[ni][h] = *(const short8*)&xT[(size_t)(16 * ni + fr) * NN + kb + 32 * h];
#pragma unroll
        for (int mi = 0; mi < 2; ++mi)
#pragma unroll
            for (int ni = 0; ni < 4; ++ni)
#pragma unroll
                for (int h = 0; h < 2; ++h)
                    acc[mi][ni] = __builtin_amdgcn_mfma_f32_16x16x32_bf16(
                        a[mi][h], b[ni][h], acc[mi][ni], 0, 0, 0);
    }
    finish_blockf(buf, acc, t, l, w, row0, h0T, xnT);
}

// ---------------------------------------------------------------------------
// Final: h = x_cl @ W2; out_ls = log_softmax(h); out_x = x_cl fp32 row-major.
// ---------------------------------------------------------------------------
__global__ __launch_bounds__(256) void final_kernel(const unsigned short* __restrict__ xT,
                                                    const float* __restrict__ W2,
                                                    float* __restrict__ out_ls,
                                                    float* __restrict__ out_x) {
    __shared__ float LS[64][65];
    const int t  = threadIdx.x;
    const int rl = t & 63;
    const int w  = t >> 6;
    const int r0 = blockIdx.x * 64;

#pragma unroll
    for (int j = 0; j < 16; ++j) {
        int c = w * 16 + j;
        LS[c][rl] = bf2f(xT[(size_t)c * NN + r0 + rl]);
    }
    __syncthreads();

#pragma unroll
    for (int k2 = 0; k2 < 16; ++k2) {
        int idx = k2 * 256 + t;
        int row = idx >> 6, col = idx & 63;
        out_x[(size_t)(r0 + row) * NH + col] = LS[col][row];
    }

    float acc[NC];
    if (t < 64) {
#pragma unroll
        for (int j = 0; j < NC; ++j) acc[j] = 0.f;
        for (int c = 0; c < NH; ++c) {
            float xv = LS[c][t];
            const float* wr = W2 + (size_t)c * NC;
#pragma unroll
            for (int j = 0; j < NC; ++j) acc[j] = fmaf(xv, wr[j], acc[j]);
        }
        float m = acc[0];
#pragma unroll
        for (int j = 1; j < NC; ++j) m = fmaxf(m, acc[j]);
        float s = 0.f;
#pragma unroll
        for (int j = 0; j < NC; ++j) s += expf(acc[j] - m);
        float lg = m + logf(s);
#pragma unroll
        for (int j = 0; j < NC; ++j) acc[j] -= lg;
    }
    __syncthreads();
    if (t < 64) {
#pragma unroll
        for (int j = 0; j < NC; ++j) LS[t][j] = acc[j];
    }
    __syncthreads();
    for (int i = t; i < 64 * NC; i += 256) {
        int row = i / NC, j = i - row * NC;
        out_ls[(size_t)r0 * NC + i] = LS[row][j];
    }
}

// ---------------------------------------------------------------------------
extern "C" void kernel_launch(void* const* d_in, const int* in_sizes, int n_in,
                              void* d_out, int out_size, void* d_ws, size_t ws_size,
                              hipStream_t stream) {
    const float* x   = (const float*)d_in[0];
    const float* adj = (const float*)d_in[1];
    const float* W1  = (const float*)d_in[2];
    const float* W2  = (const float*)d_in[3];

    float* out_ls = (float*)d_out;                      // 16384*40 fp32
    float* out_x  = out_ls + (size_t)NN * NC;           // 16384*64 fp32

    const size_t xbytes  = (size_t)NN * NH * sizeof(unsigned short);  // 2 MiB
    const size_t x8bytes = (size_t)NN * NH;                           // 1 MiB
    char* ws = (char*)d_ws;

    unsigned short *h0T, *xa, *xb;
    unsigned char  *xa8, *xb8;
    size_t used;
    if (ws_size >= 3 * xbytes + 2 * x8bytes) {
        h0T = (unsigned short*)ws;
        xa  = (unsigned short*)(ws + xbytes);
        xb  = (unsigned short*)(ws + 2 * xbytes);
        xa8 = (unsigned char*)(ws + 3 * xbytes);
        xb8 = xa8 + x8bytes;
        used = 3 * xbytes + 2 * x8bytes;
    } else {
        xa  = (unsigned short*)ws;
        xb  = xa + (size_t)NN * NH;
        h0T = (unsigned short*)out_ls;   // overwritten only by final_kernel
        xa8 = xb8 = nullptr;
        used = 2 * xbytes;
    }
    used = (used + 255) & ~(size_t)255;

    const size_t pbytes    = (size_t)PKH * NN * NH * sizeof(unsigned short); // 16 MiB
    const size_t adj8bytes = (size_t)NN * NN;                                // 256 MiB

    unsigned short* P = nullptr;
    unsigned char* adjT8 = nullptr;
    if (xa8 && ws_size >= used + pbytes + adj8bytes) {
        P     = (unsigned short*)(ws + used);
        adjT8 = (unsigned char*)(ws + used + pbytes);
    }

    h0_kernel<<<NN / 64, 256, 0, stream>>>(x, W1, h0T);

    unsigned short* cur  = h0T;   // x0 = h0
    unsigned short* nxt  = xa;
    unsigned char*  cur8 = nullptr;
    unsigned char*  nxt8 = xa8;

    for (int s = 0; s < KSTEPS; ++s) {
        if (adjT8) {
            if (s == 0)
                step0_kernel<<<(NN / 16) * PKH / 8 * 8, 512, 0, stream>>>(adj, adjT8, cur, P);
            else
                stept_kernel<<<(NN / 256) * PKH, 512, 0, stream>>>(adjT8, cur8, P);
            combine_kernel<<<NN / 64, 256, 0, stream>>>(
                P, h0T, nxt, nxt8, (s == 0) ? 0.9f : 0.9f / ASCALE);
        } else {
            stepf_kernel<<<NN / BM, 512, 0, stream>>>(adj, cur, h0T, nxt);
        }
        unsigned short* ts  = (cur == h0T) ? xb : cur;
        unsigned char*  ts8 = (cur8 == nullptr) ? xb8 : cur8;
        cur = nxt;   nxt = ts;
        cur8 = nxt8; nxt8 = ts8;
    }

    final_kernel<<<NN / 64, 256, 0, stream>>>(cur, W2, out_ls, out_x);
}